// Round 3
// baseline (1019.733 us; speedup 1.0000x reference)
//
#include <hip/hip_runtime.h>
#include <hip/hip_fp16.h>

#define NN 100000
#define NE 3200000
#define HID 64

// Workspace layout (int/float units of 4B):
//  [0,NN)        deg      (later overlaid by p)
//  [NN,2NN)      s1       (fp32, atomically accumulated)
//  [2NN,3NN)     base     (later overlaid by s3)
//  [3NN,4NN)     cursor   (== segment end after scatter)
//  [4NN,4NN+256) blksum
//  [4NN+256,5NN+256) r
//  [5NN+256, +2NE)   rec  (int2 per edge: .x = w bits, .y = half2(s1[src], x[src]))
// Total = 5*NN+256 + 2*NE ints = 27.6 MB (same as round 2 -> fits ws).

// -------- count degrees + accumulate s1 = segment_sum(w * x[src]) --------
__global__ void k_count_s1(const int* __restrict__ src, const int* __restrict__ dst,
                           const float* __restrict__ ew, const float* __restrict__ x,
                           int* __restrict__ deg, float* __restrict__ s1) {
    int e = blockIdx.x * blockDim.x + threadIdx.x;
    if (e < NE) {
        int d = dst[e];
        atomicAdd(&deg[d], 1);
        atomicAdd(&s1[d], ew[e] * x[src[e]]);
    }
}

// -------- per-block exclusive scan (1024/block) --------
__global__ void k_scan_block(const int* __restrict__ deg, int* __restrict__ base,
                             int* __restrict__ blksum) {
    __shared__ int sh[1024];
    const int tid = threadIdx.x;
    const int i = blockIdx.x * 1024 + tid;
    int v = (i < NN) ? deg[i] : 0;
    sh[tid] = v;
    __syncthreads();
    #pragma unroll
    for (int off = 1; off < 1024; off <<= 1) {
        int t = (tid >= off) ? sh[tid - off] : 0;
        __syncthreads();
        sh[tid] += t;
        __syncthreads();
    }
    if (i < NN) base[i] = sh[tid] - v;
    if (tid == 1023) blksum[blockIdx.x] = sh[1023];
}

__global__ void k_scan_top(int* __restrict__ blksum, int nb) {
    __shared__ int sh[128];
    const int tid = threadIdx.x;
    int v = (tid < nb) ? blksum[tid] : 0;
    sh[tid] = v;
    __syncthreads();
    #pragma unroll
    for (int off = 1; off < 128; off <<= 1) {
        int t = (tid >= off) ? sh[tid - off] : 0;
        __syncthreads();
        sh[tid] += t;
        __syncthreads();
    }
    if (tid < nb) blksum[tid] = sh[tid] - v;
}

__global__ void k_scan_add(const int* __restrict__ blksum, int* __restrict__ base,
                           int* __restrict__ cursor) {
    int i = blockIdx.x * blockDim.x + threadIdx.x;
    if (i < NN) {
        int b = base[i] + blksum[i >> 10];
        base[i] = b;
        cursor[i] = b;
    }
}

// -------- scatter pre-gathered records sorted by dst --------
__global__ void k_scatter(const int* __restrict__ src, const int* __restrict__ dst,
                          const float* __restrict__ ew,
                          const float* __restrict__ s1, const float* __restrict__ x,
                          int* __restrict__ cursor, int2* __restrict__ rec) {
    int e = blockIdx.x * blockDim.x + threadIdx.x;
    if (e < NE) {
        int d = dst[e];
        int s = src[e];
        __half2 hv = __floats2half2_rn(s1[s], x[s]);
        int pos = atomicAdd(&cursor[d], 1);
        rec[pos] = make_int2(__float_as_int(ew[e]), *(const int*)&hv);
    }
}

// -------- fused layer-2 gather + node matmuls + layer-3 projections --------
__global__ __launch_bounds__(256) void k_l2_fused(
        const int* __restrict__ base, const int* __restrict__ endp,
        const int2* __restrict__ rec,
        const float* __restrict__ s1, const float* __restrict__ x,
        const float* __restrict__ W1_rel, const float* __restrict__ W1_root,
        const float* __restrict__ b1,
        const float* __restrict__ W2_rel, const float* __restrict__ b2,
        const float* __restrict__ W2_root,
        const float* __restrict__ W3_rel, const float* __restrict__ W3_root,
        float* __restrict__ p, float* __restrict__ r) {
    __shared__ float2 lw2[HID * HID];        // (W2_rel[k,f], W2_root[k,f]) interleaved
    for (int t = threadIdx.x; t < HID * HID; t += 256)
        lw2[t] = make_float2(W2_rel[t], W2_root[t]);
    __syncthreads();

    const int f = threadIdx.x & 63;
    const int i = (blockIdx.x * blockDim.x + threadIdx.x) >> 6;   // one node per wave
    if (i >= NN) return;

    const float w1r = W1_rel[f], w1t = W1_root[f], b1f = b1[f];

    float acc0 = 0.f, acc1 = 0.f;
    const int beg = base[i];
    const int cnt = endp[i] - beg;
    for (int c = 0; c < cnt; c += 64) {
        int2 rc = make_int2(0, 0);           // pad: w=0, a=b=0
        if (c + f < cnt) rc = rec[beg + c + f];
        const float  wE = __int_as_float(rc.x);
        const __half2 hv = *(const __half2*)&rc.y;
        const float  aE = __low2float(hv);   // s1[src] (fp16-rounded)
        const float  bE = __high2float(hv);  // x[src]
        const int rem = cnt - c;             // wave-uniform
        #pragma unroll
        for (int chunk = 0; chunk < 4; ++chunk) {
            if (chunk * 16 < rem) {          // wave-uniform branch
                #pragma unroll
                for (int kk = 0; kk < 16; ++kk) {
                    const int k = chunk * 16 + kk;
                    const float wk = __shfl(wE, k, 64);
                    const float ak = __shfl(aE, k, 64);
                    const float bk = __shfl(bE, k, 64);
                    const float h = fmaxf(0.f, fmaf(ak, w1r, fmaf(bk, w1t, b1f)));
                    if (kk & 1) acc1 = fmaf(wk, h, acc1);
                    else        acc0 = fmaf(wk, h, acc0);
                }
            }
        }
    }
    const float acc = acc0 + acc1;

    // root term at full precision
    const float hi = fmaxf(0.f, fmaf(s1[i], w1r, fmaf(x[i], w1t, b1f)));

    float o = b2[f];
    #pragma unroll
    for (int k = 0; k < HID; ++k) {
        const float2 wv = lw2[k * HID + f];  // ds_read_b64, conflict-free
        const float ak = __shfl(acc, k, 64);
        const float hk = __shfl(hi, k, 64);
        o = fmaf(ak, wv.x, fmaf(hk, wv.y, o));
    }
    const float h2 = fmaxf(0.f, o);

    float pv = h2 * W3_rel[f];
    float rv = h2 * W3_root[f];
    #pragma unroll
    for (int off = 32; off; off >>= 1) {
        pv += __shfl_down(pv, off, 64);
        rv += __shfl_down(rv, off, 64);
    }
    if (f == 0) { p[i] = pv; r[i] = rv; }
}

// -------- layer-3 scalar aggregation (atomic; s3 pre-zeroed) --------
__global__ void k_final_atomic(const int* __restrict__ src, const int* __restrict__ dst,
                               const float* __restrict__ ew, const float* __restrict__ p,
                               float* __restrict__ s3) {
    int e = blockIdx.x * blockDim.x + threadIdx.x;
    if (e < NE) atomicAdd(&s3[dst[e]], ew[e] * p[src[e]]);
}

__global__ void k_finalize(const float* __restrict__ s3, const float* __restrict__ r,
                           const float* __restrict__ b3, float* __restrict__ out) {
    int i = blockIdx.x * blockDim.x + threadIdx.x;
    if (i < NN) out[i] = s3[i] + r[i] + b3[0];
}

extern "C" void kernel_launch(void* const* d_in, const int* in_sizes, int n_in,
                              void* d_out, int out_size, void* d_ws, size_t ws_size,
                              hipStream_t stream) {
    const float* x       = (const float*)d_in[0];
    const int*   ei      = (const int*)  d_in[1];
    const float* ew      = (const float*)d_in[2];
    const float* W1_rel  = (const float*)d_in[3];
    const float* b1      = (const float*)d_in[4];
    const float* W1_root = (const float*)d_in[5];
    const float* W2_rel  = (const float*)d_in[6];
    const float* b2      = (const float*)d_in[7];
    const float* W2_root = (const float*)d_in[8];
    const float* W3_rel  = (const float*)d_in[9];
    const float* b3      = (const float*)d_in[10];
    const float* W3_root = (const float*)d_in[11];

    const int* src = ei;
    const int* dst = ei + NE;

    int*   iws    = (int*)d_ws;
    int*   deg    = iws;                       // [0,NN)
    float* s1     = (float*)(iws + NN);        // [NN,2NN)
    int*   base   = iws + 2 * NN;              // [2NN,3NN)
    int*   cursor = iws + 3 * NN;              // [3NN,4NN)
    int*   blksum = iws + 4 * NN;              // 256
    float* r      = (float*)(iws + 4 * NN + 256);
    int2*  rec    = (int2*)(iws + 5 * NN + 256);
    float* p      = (float*)deg;               // overlay: deg dead after scans
    float* s3     = (float*)base;              // overlay: base dead after l2_fused

    // zero deg + s1 (contiguous)
    hipMemsetAsync(iws, 0, (size_t)2 * NN * sizeof(int), stream);

    const int eb  = (NE + 255) / 256;
    const int nb1 = (NN + 1023) / 1024;        // 98
    const int wb  = (NN * 64) / 256;           // 25000 blocks, 1 wave/node

    k_count_s1<<<eb, 256, 0, stream>>>(src, dst, ew, x, deg, s1);
    k_scan_block<<<nb1, 1024, 0, stream>>>(deg, base, blksum);
    k_scan_top<<<1, 128, 0, stream>>>(blksum, nb1);
    k_scan_add<<<(NN + 255) / 256, 256, 0, stream>>>(blksum, base, cursor);
    k_scatter<<<eb, 256, 0, stream>>>(src, dst, ew, s1, x, cursor, rec);
    // cursor[i] == segment end

    k_l2_fused<<<wb, 256, 0, stream>>>(base, cursor, rec, s1, x,
                                       W1_rel, W1_root, b1,
                                       W2_rel, b2, W2_root,
                                       W3_rel, W3_root, p, r);

    hipMemsetAsync(s3, 0, (size_t)NN * sizeof(float), stream);   // zero s3 overlay
    k_final_atomic<<<eb, 256, 0, stream>>>(src, dst, ew, p, s3);
    k_finalize<<<(NN + 255) / 256, 256, 0, stream>>>(s3, r, b3, (float*)d_out);
}

// Round 4
// 769.432 us; speedup vs baseline: 1.3253x; 1.3253x over previous
//
#include <hip/hip_runtime.h>

#define NN 100000
#define NE 3200000
#define HID 64

// Workspace layout (4B units), total 5*NN+256+2*NE = 27.6 MB (proven fit in R2):
//  [0,NN)            deg   (int)   -> overlaid by p (float) after scans
//  [NN,2NN)          base
//  [2NN,3NN)         cursor (== segment end after scatter)
//  [3NN,4NN)         s1    (float)
//  [4NN,4NN+256)     blksum
//  [4NN+256,5NN+256) r     (float)
//  [5NN+256,+2NE)    rec   (int2: .x=src, .y=ew bits)

__global__ void k_count(const int* __restrict__ dst, int* __restrict__ deg) {
    int e = blockIdx.x * blockDim.x + threadIdx.x;
    if (e < NE) atomicAdd(&deg[dst[e]], 1);
}

__global__ void k_scan_block(const int* __restrict__ deg, int* __restrict__ base,
                             int* __restrict__ blksum) {
    __shared__ int sh[1024];
    const int tid = threadIdx.x;
    const int i = blockIdx.x * 1024 + tid;
    int v = (i < NN) ? deg[i] : 0;
    sh[tid] = v;
    __syncthreads();
    #pragma unroll
    for (int off = 1; off < 1024; off <<= 1) {
        int t = (tid >= off) ? sh[tid - off] : 0;
        __syncthreads();
        sh[tid] += t;
        __syncthreads();
    }
    if (i < NN) base[i] = sh[tid] - v;
    if (tid == 1023) blksum[blockIdx.x] = sh[1023];
}

__global__ void k_scan_top(int* __restrict__ blksum, int nb) {
    __shared__ int sh[128];
    const int tid = threadIdx.x;
    int v = (tid < nb) ? blksum[tid] : 0;
    sh[tid] = v;
    __syncthreads();
    #pragma unroll
    for (int off = 1; off < 128; off <<= 1) {
        int t = (tid >= off) ? sh[tid - off] : 0;
        __syncthreads();
        sh[tid] += t;
        __syncthreads();
    }
    if (tid < nb) blksum[tid] = sh[tid] - v;
}

__global__ void k_scan_add(const int* __restrict__ blksum, int* __restrict__ base,
                           int* __restrict__ cursor) {
    int i = blockIdx.x * blockDim.x + threadIdx.x;
    if (i < NN) {
        int b = base[i] + blksum[i >> 10];
        base[i] = b;
        cursor[i] = b;
    }
}

__global__ void k_scatter(const int* __restrict__ src, const int* __restrict__ dst,
                          const float* __restrict__ ew, int* __restrict__ cursor,
                          int2* __restrict__ rec) {
    int e = blockIdx.x * blockDim.x + threadIdx.x;
    if (e < NE) {
        int d = dst[e];
        int pos = atomicAdd(&cursor[d], 1);
        rec[pos] = make_int2(src[e], __float_as_int(ew[e]));
    }
}

// -------- scalar CSR gather: out[i] = sum w*val[src] (+ radd[i] + b[0]) --------
__global__ __launch_bounds__(256) void k_gather_scalar(
        const int* __restrict__ base, const int* __restrict__ endp,
        const int2* __restrict__ rec, const float* __restrict__ val,
        const float* __restrict__ radd, const float* __restrict__ bias,
        float* __restrict__ out) {
    const int i = (blockIdx.x * blockDim.x + threadIdx.x) >> 6;
    const int lane = threadIdx.x & 63;
    if (i >= NN) return;
    const int beg = base[i], end = endp[i];
    float acc = 0.f;
    for (int e = beg + lane; e < end; e += 64) {
        int2 rc = rec[e];
        acc = fmaf(__int_as_float(rc.y), val[rc.x], acc);
    }
    #pragma unroll
    for (int off = 32; off; off >>= 1) acc += __shfl_down(acc, off, 64);
    if (lane == 0) {
        float o = acc;
        if (radd) o += radd[i] + bias[0];
        out[i] = o;
    }
}

// helper: broadcast read of lane k's value via v_readlane (VALU pipe, NOT ds_bpermute)
__device__ __forceinline__ float rdlane(float v, int k) {
    return __int_as_float(__builtin_amdgcn_readlane(__float_as_int(v), k));
}

// -------- fused layer-2: shuffle-free --------
// wave-per-node (persistent). Edge loop: all lanes broadcast-load rec + s1/x gathers.
// Epilogue: W2 columns in 128 VGPRs, acc/hi broadcast via v_readlane.
__global__ __launch_bounds__(256, 2) void k_l2_fused(
        const int* __restrict__ base, const int* __restrict__ endp,
        const int2* __restrict__ rec,
        const float* __restrict__ s1, const float* __restrict__ x,
        const float* __restrict__ W1_rel, const float* __restrict__ W1_root,
        const float* __restrict__ b1,
        const float* __restrict__ W2_rel, const float* __restrict__ b2,
        const float* __restrict__ W2_root,
        const float* __restrict__ W3_rel, const float* __restrict__ W3_root,
        float* __restrict__ p, float* __restrict__ r) {
    const int f = threadIdx.x & 63;

    // per-lane W2 columns -> registers (coalesced 256B rows, once per wave)
    float wrel[HID], wroot[HID];
    #pragma unroll
    for (int k = 0; k < HID; ++k) {
        wrel[k]  = W2_rel[k * HID + f];
        wroot[k] = W2_root[k * HID + f];
    }
    const float w1r = W1_rel[f], w1t = W1_root[f], b1f = b1[f];
    const float w3r = W3_rel[f], w3t = W3_root[f], b2f = b2[f];

    const int wid = (blockIdx.x * blockDim.x + threadIdx.x) >> 6;
    const int nw  = (gridDim.x * blockDim.x) >> 6;

    for (int i = wid; i < NN; i += nw) {
        const int beg = base[i], end = endp[i];
        float a0 = 0.f, a1 = 0.f, a2 = 0.f, a3 = 0.f;
        int e = beg;
        for (; e + 8 <= end; e += 8) {
            // 8 broadcast record loads (sequential, cache-friendly)
            int2 q0 = rec[e],     q1 = rec[e + 1], q2 = rec[e + 2], q3 = rec[e + 3];
            int2 q4 = rec[e + 4], q5 = rec[e + 5], q6 = rec[e + 6], q7 = rec[e + 7];
            // 16 broadcast gathers from L2-resident 400KB tables
            float s0 = s1[q0.x], x0 = x[q0.x];
            float s1v = s1[q1.x], x1 = x[q1.x];
            float s2 = s1[q2.x], x2 = x[q2.x];
            float s3 = s1[q3.x], x3 = x[q3.x];
            float s4 = s1[q4.x], x4 = x[q4.x];
            float s5 = s1[q5.x], x5 = x[q5.x];
            float s6 = s1[q6.x], x6 = x[q6.x];
            float s7 = s1[q7.x], x7 = x[q7.x];
            a0 = fmaf(__int_as_float(q0.y), fmaxf(0.f, fmaf(s0,  w1r, fmaf(x0, w1t, b1f))), a0);
            a1 = fmaf(__int_as_float(q1.y), fmaxf(0.f, fmaf(s1v, w1r, fmaf(x1, w1t, b1f))), a1);
            a2 = fmaf(__int_as_float(q2.y), fmaxf(0.f, fmaf(s2,  w1r, fmaf(x2, w1t, b1f))), a2);
            a3 = fmaf(__int_as_float(q3.y), fmaxf(0.f, fmaf(s3,  w1r, fmaf(x3, w1t, b1f))), a3);
            a0 = fmaf(__int_as_float(q4.y), fmaxf(0.f, fmaf(s4,  w1r, fmaf(x4, w1t, b1f))), a0);
            a1 = fmaf(__int_as_float(q5.y), fmaxf(0.f, fmaf(s5,  w1r, fmaf(x5, w1t, b1f))), a1);
            a2 = fmaf(__int_as_float(q6.y), fmaxf(0.f, fmaf(s6,  w1r, fmaf(x6, w1t, b1f))), a2);
            a3 = fmaf(__int_as_float(q7.y), fmaxf(0.f, fmaf(s7,  w1r, fmaf(x7, w1t, b1f))), a3);
        }
        for (; e < end; ++e) {
            int2 q0 = rec[e];
            a0 = fmaf(__int_as_float(q0.y),
                      fmaxf(0.f, fmaf(s1[q0.x], w1r, fmaf(x[q0.x], w1t, b1f))), a0);
        }
        const float acc = (a0 + a1) + (a2 + a3);
        const float hi  = fmaxf(0.f, fmaf(s1[i], w1r, fmaf(x[i], w1t, b1f)));

        // 64x64 x2 matmul row: readlane broadcasts + register weights (pure VALU)
        float o0 = b2f, o1 = 0.f, o2 = 0.f, o3 = 0.f;
        #pragma unroll
        for (int k = 0; k < HID; k += 4) {
            o0 = fmaf(rdlane(acc, k    ), wrel[k    ], fmaf(rdlane(hi, k    ), wroot[k    ], o0));
            o1 = fmaf(rdlane(acc, k + 1), wrel[k + 1], fmaf(rdlane(hi, k + 1), wroot[k + 1], o1));
            o2 = fmaf(rdlane(acc, k + 2), wrel[k + 2], fmaf(rdlane(hi, k + 2), wroot[k + 2], o2));
            o3 = fmaf(rdlane(acc, k + 3), wrel[k + 3], fmaf(rdlane(hi, k + 3), wroot[k + 3], o3));
        }
        const float h2 = fmaxf(0.f, (o0 + o1) + (o2 + o3));

        float pv = h2 * w3r;
        float rv = h2 * w3t;
        #pragma unroll
        for (int off = 32; off; off >>= 1) {
            pv += __shfl_down(pv, off, 64);
            rv += __shfl_down(rv, off, 64);
        }
        if (f == 0) { p[i] = pv; r[i] = rv; }
    }
}

extern "C" void kernel_launch(void* const* d_in, const int* in_sizes, int n_in,
                              void* d_out, int out_size, void* d_ws, size_t ws_size,
                              hipStream_t stream) {
    const float* x       = (const float*)d_in[0];
    const int*   ei      = (const int*)  d_in[1];
    const float* ew      = (const float*)d_in[2];
    const float* W1_rel  = (const float*)d_in[3];
    const float* b1      = (const float*)d_in[4];
    const float* W1_root = (const float*)d_in[5];
    const float* W2_rel  = (const float*)d_in[6];
    const float* b2      = (const float*)d_in[7];
    const float* W2_root = (const float*)d_in[8];
    const float* W3_rel  = (const float*)d_in[9];
    const float* b3      = (const float*)d_in[10];
    const float* W3_root = (const float*)d_in[11];

    const int* src = ei;
    const int* dst = ei + NE;

    int*   iws    = (int*)d_ws;
    int*   deg    = iws;                       // [0,NN)
    int*   base   = iws + NN;                  // [NN,2NN)
    int*   cursor = iws + 2 * NN;              // [2NN,3NN)
    float* s1     = (float*)(iws + 3 * NN);    // [3NN,4NN)
    int*   blksum = iws + 4 * NN;              // 256
    float* r      = (float*)(iws + 4 * NN + 256);
    int2*  rec    = (int2*)(iws + 5 * NN + 256);
    float* p      = (float*)deg;               // overlay: deg dead after scans

    hipMemsetAsync(deg, 0, (size_t)NN * sizeof(int), stream);

    const int eb  = (NE + 255) / 256;
    const int nb1 = (NN + 1023) / 1024;        // 98
    const int wb  = (NN * 64) / 256;           // 25000 blocks, wave-per-node

    k_count<<<eb, 256, 0, stream>>>(dst, deg);
    k_scan_block<<<nb1, 1024, 0, stream>>>(deg, base, blksum);
    k_scan_top<<<1, 128, 0, stream>>>(blksum, nb1);
    k_scan_add<<<(NN + 255) / 256, 256, 0, stream>>>(blksum, base, cursor);
    k_scatter<<<eb, 256, 0, stream>>>(src, dst, ew, cursor, rec);
    // cursor[i] == segment end

    // s1 = segment_sum(w * x[src])
    k_gather_scalar<<<wb, 256, 0, stream>>>(base, cursor, rec, x,
                                            nullptr, nullptr, s1);

    // persistent: 512 blocks -> 2048 waves, ~49 nodes each
    k_l2_fused<<<512, 256, 0, stream>>>(base, cursor, rec, s1, x,
                                        W1_rel, W1_root, b1,
                                        W2_rel, b2, W2_root,
                                        W3_rel, W3_root, p, r);

    // out = segment_sum(w * p[src]) + r + b3
    k_gather_scalar<<<wb, 256, 0, stream>>>(base, cursor, rec, p,
                                            r, b3, (float*)d_out);
}